// Round 14
// baseline (296.108 us; speedup 1.0000x reference)
//
#include <hip/hip_runtime.h>
#include <hip/hip_fp16.h>
#include <math.h>

#define B_      64
#define N_      1024
#define D_      768
#define T_      16
#define SLABS   32
#define ROWS_PB 32
#define ROWS_PW 8
#define THR     256
#define CPL     24
#define NTILE   36          // upper-triangle 8x8 tile grid
#define WFG     8           // k_wf row groups
#define WFTHR   192         // k_wf threads (4 cols each)

typedef _Float16 half8 __attribute__((ext_vector_type(8)));
typedef float    f32x4 __attribute__((ext_vector_type(4)));

__device__ __forceinline__ float wave_sum(float v) {
    #pragma unroll
    for (int off = 32; off; off >>= 1) v += __shfl_xor(v, off);
    return v;
}
__device__ __forceinline__ float half_sum(float v) {
    #pragma unroll
    for (int off = 16; off; off >>= 1) v += __shfl_xor(v, off);
    return v;
}
__device__ __forceinline__ unsigned pack2(float a, float b) {
    __half2 h = __float22half2_rn(make_float2(a, b));
    return *(unsigned*)&h;
}
__device__ __forceinline__ void unpack8(uint4 u, float* f) {
    __half2 h; float2 q;
    h = *(__half2*)&u.x; q = __half22float2(h); f[0] = q.x; f[1] = q.y;
    h = *(__half2*)&u.y; q = __half22float2(h); f[2] = q.x; f[3] = q.y;
    h = *(__half2*)&u.z; q = __half22float2(h); f[4] = q.x; f[5] = q.y;
    h = *(__half2*)&u.w; q = __half22float2(h); f[6] = q.x; f[7] = q.y;
}

// async global->LDS, 16B per lane (dest = wave-uniform base + lane*16, G21)
__device__ __forceinline__ void gload_lds16(const void* g, void* l) {
    __builtin_amdgcn_global_load_lds(
        (__attribute__((address_space(1))) void*)(g),
        (__attribute__((address_space(3))) void*)(l), 16, 0, 0);
}

// ---------------- pass 0: saliency + f16 pack ----------------
__global__ __launch_bounds__(THR)
void k_sal16v(const float* __restrict__ feat, ushort* __restrict__ f16,
              float* __restrict__ sal, float* __restrict__ rsal,
              float* __restrict__ mask, float* __restrict__ argv,
              float* __restrict__ args, int* __restrict__ argi) {
    const int blk = blockIdx.x, b = blk >> 5, g = blk & 31;
    const int tid = threadIdx.x, wave = tid >> 6, lane = tid & 63;
    const int h = lane >> 5, s = lane & 31;
    __shared__ float s_sal[ROWS_PB];

    const size_t row0 = (size_t)b * N_ + (size_t)g * ROWS_PB;
    const int r0 = wave * ROWS_PW;

    #pragma unroll
    for (int rp = 0; rp < ROWS_PW / 2; ++rp) {
        const int r = r0 + rp * 2 + h;
        const float4* fp4 = (const float4*)(feat + (row0 + r) * D_ + s * CPL);
        float4 a0 = fp4[0], a1 = fp4[1], a2 = fp4[2], a3 = fp4[3], a4 = fp4[4], a5 = fp4[5];
        uint4 w0, w1, w2;
        w0.x = pack2(a0.x, a0.y); w0.y = pack2(a0.z, a0.w);
        w0.z = pack2(a1.x, a1.y); w0.w = pack2(a1.z, a1.w);
        w1.x = pack2(a2.x, a2.y); w1.y = pack2(a2.z, a2.w);
        w1.z = pack2(a3.x, a3.y); w1.w = pack2(a3.z, a3.w);
        w2.x = pack2(a4.x, a4.y); w2.y = pack2(a4.z, a4.w);
        w2.z = pack2(a5.x, a5.y); w2.w = pack2(a5.z, a5.w);
        uint4* wp = (uint4*)(f16 + (row0 + r) * D_ + s * CPL);
        wp[0] = w0; wp[1] = w1; wp[2] = w2;

        float ss = a0.x*a0.x + a0.y*a0.y + a0.z*a0.z + a0.w*a0.w
                 + a1.x*a1.x + a1.y*a1.y + a1.z*a1.z + a1.w*a1.w
                 + a2.x*a2.x + a2.y*a2.y + a2.z*a2.z + a2.w*a2.w
                 + a3.x*a3.x + a3.y*a3.y + a3.z*a3.z + a3.w*a3.w
                 + a4.x*a4.x + a4.y*a4.y + a4.z*a4.z + a4.w*a4.w
                 + a5.x*a5.x + a5.y*a5.y + a5.z*a5.z + a5.w*a5.w;
        ss = half_sum(ss);
        if (s == 0) s_sal[r] = sqrtf(ss);
    }
    __syncthreads();

    const int rg = b * N_ + g * ROWS_PB;
    if (tid < ROWS_PB) {
        float n = s_sal[tid];
        sal[rg + tid]  = n;
        rsal[rg + tid] = 1.0f / fmaxf(n, 1e-12f);
        mask[rg + tid] = 1.0f;
    }
    if (wave == 0) {
        float v  = (lane < ROWS_PB) ? s_sal[lane] : -INFINITY;
        float sv = v;
        int   i  = (lane < ROWS_PB) ? (g * ROWS_PB + lane) : 0x7fffffff;
        #pragma unroll
        for (int off = 32; off; off >>= 1) {
            float ov = __shfl_xor(v, off);
            float osv = __shfl_xor(sv, off);
            int   oi = __shfl_xor(i, off);
            if (ov > v || (ov == v && oi < i)) { v = ov; sv = osv; i = oi; }
        }
        if (lane == 0) { argv[b*SLABS+g] = v; args[b*SLABS+g] = sv; argi[b*SLABS+g] = i; }
    }
}

// ---------------- Gram GEMM (upper-triangle, XCD-grouped, gload_lds, f32 G) ----------------
// __launch_bounds__(256, 4): cap regs at 128/wave -> 4 blocks/CU (was 3, VGPR-capped)
__global__ __launch_bounds__(THR, 4)
void k_gram(const ushort* __restrict__ f16, float* __restrict__ G) {
    const int bid = blockIdx.x;
    const int xcd = bid & 7, slot = bid >> 3;
    const int batch = xcd + 8 * (slot / NTILE);
    int u = slot % NTILE;
    int trow = 0, cnt = 8;
    while (u >= cnt) { u -= cnt; --cnt; ++trow; }
    const int tcol = trow + u;
    const bool diag = (trow == tcol);

    const int tid = threadIdx.x, wave = tid >> 6, lane = tid & 63;
    const int wr = wave >> 1, wc = wave & 1;

    __shared__ __align__(16) ushort lA[128 * 64];
    __shared__ __align__(16) ushort lB[128 * 64];

    const ushort* Fb = f16 + (size_t)batch * N_ * D_;
    const int row0 = trow * 128, col0 = tcol * 128;

    f32x4 acc[4][4];
    #pragma unroll
    for (int i = 0; i < 4; ++i)
        #pragma unroll
        for (int j = 0; j < 4; ++j)
            acc[i][j] = (f32x4){0.f, 0.f, 0.f, 0.f};

    const ushort* lBr = diag ? lA : lB;

    for (int k0 = 0; k0 < D_; k0 += 64) {
        #pragma unroll
        for (int i = 0; i < 4; ++i) {
            const int d  = i * THR + tid;
            const int r  = d >> 3;
            const int kc = (d & 7) ^ (r & 7);
            gload_lds16(Fb + (size_t)(row0 + r) * D_ + k0 + kc * 8, lA + (size_t)d * 8);
            if (!diag)
                gload_lds16(Fb + (size_t)(col0 + r) * D_ + k0 + kc * 8, lB + (size_t)d * 8);
        }
        __syncthreads();

        #pragma unroll
        for (int ks = 0; ks < 2; ++ks) {
            half8 af[4], bf[4];
            #pragma unroll
            for (int fr = 0; fr < 4; ++fr) {
                const int rl = wr * 64 + fr * 16 + (lane & 15);
                const int kch = ks * 4 + (lane >> 4);
                af[fr] = *(const half8*)(lA + rl * 64 + ((kch ^ (rl & 7)) * 8));
            }
            #pragma unroll
            for (int fc = 0; fc < 4; ++fc) {
                const int cl = wc * 64 + fc * 16 + (lane & 15);
                const int kch = ks * 4 + (lane >> 4);
                bf[fc] = *(const half8*)(lBr + cl * 64 + ((kch ^ (cl & 7)) * 8));
            }
            #pragma unroll
            for (int fr = 0; fr < 4; ++fr)
                #pragma unroll
                for (int fc = 0; fc < 4; ++fc)
                    acc[fr][fc] = __builtin_amdgcn_mfma_f32_16x16x32_f16(
                        af[fr], bf[fc], acc[fr][fc], 0, 0, 0);
        }
        __syncthreads();
    }

    // epilogue: C/D mapping col=lane&15, row=(lane>>4)*4+q  [m89]
    float* Gb = G + ((size_t)batch << 20);
    #pragma unroll
    for (int fr = 0; fr < 4; ++fr) {
        #pragma unroll
        for (int fc = 0; fc < 4; ++fc) {
            const int rbase = row0 + wr * 64 + fr * 16 + (lane >> 4) * 4;
            const int c     = col0 + wc * 64 + fc * 16 + (lane & 15);
            #pragma unroll
            for (int q = 0; q < 4; ++q)
                Gb[(size_t)(rbase + q) * N_ + c] = acc[fr][fc][q];
        }
    }
}

// ---------------- slot loop: 1 wave per batch, register state, zero barriers ----------------
__global__ __launch_bounds__(64)
void k_slots(const float* __restrict__ G, const float* __restrict__ sal,
             const float* __restrict__ rsal, float* __restrict__ wbuf) {
    const int b = blockIdx.x, lane = threadIdx.x;
    const float* Gb = G + ((size_t)b << 20);

    float lsal[16], lrsal[16], lmask[16], lmsal[16];
    #pragma unroll
    for (int k = 0; k < 16; ++k) {
        const int n = lane + (k << 6);
        lsal[k]  = sal[b * N_ + n];
        lrsal[k] = rsal[b * N_ + n];
        lmask[k] = 1.0f;
        lmsal[k] = lsal[k];
    }

    for (int t = 0; t < T_; ++t) {
        float v = lmsal[0]; int i = lane;
        #pragma unroll
        for (int k = 1; k < 16; ++k) {
            if (lmsal[k] > v) { v = lmsal[k]; i = lane + (k << 6); }
        }
        #pragma unroll
        for (int off = 32; off; off >>= 1) {
            float ov = __shfl_xor(v, off);
            int   oi = __shfl_xor(i, off);
            if (ov > v || (ov == v && oi < i)) { v = ov; i = oi; }
        }
        const int idx = i;

        // rsi from registers: idx>>6 is wave-uniform -> uniform switch, then shfl
        const int ko = idx >> 6, lo = idx & 63;
        float x;
        switch (ko) {
            case 0:  x = lrsal[0];  break;
            case 1:  x = lrsal[1];  break;
            case 2:  x = lrsal[2];  break;
            case 3:  x = lrsal[3];  break;
            case 4:  x = lrsal[4];  break;
            case 5:  x = lrsal[5];  break;
            case 6:  x = lrsal[6];  break;
            case 7:  x = lrsal[7];  break;
            case 8:  x = lrsal[8];  break;
            case 9:  x = lrsal[9];  break;
            case 10: x = lrsal[10]; break;
            case 11: x = lrsal[11]; break;
            case 12: x = lrsal[12]; break;
            case 13: x = lrsal[13]; break;
            case 14: x = lrsal[14]; break;
            default: x = lrsal[15]; break;
        }
        const float rsi = __shfl(x, lo);

        #pragma unroll
        for (int k = 0; k < 16; ++k) {
            const int n = lane + (k << 6);
            float gv  = (n >= idx) ? Gb[(size_t)idx * N_ + n]
                                   : Gb[(size_t)n * N_ + idx];
            float sim = gv * lrsal[k] * rsi;
            float m   = lmask[k];
            float w   = (sim > 0.5f) ? (sim * m) : 0.f;
            float nm  = m * (1.0f - fminf(fmaxf(sim, 0.f), 1.f));
            lmask[k] = nm;
            lmsal[k] = lsal[k] * nm;
            wbuf[((size_t)(b * T_ + t)) * N_ + n] = w;
        }
    }
}

// ---------------- W*F partials + per-rg wsum partials ----------------
__global__ __launch_bounds__(WFTHR)
void k_wf(const ushort* __restrict__ f16, const float* __restrict__ wbuf,
          float* __restrict__ part, float* __restrict__ wsp) {
    const int bid = blockIdx.x, b = bid >> 3, rg = bid & 7;
    const int tid = threadIdx.x;
    const int RPG = N_ / WFG;

    __shared__ float s_w[T_ * (N_ / WFG)];

    for (int idx = tid; idx < T_ * RPG; idx += WFTHR) {
        const int t = idx >> 7, r = idx & 127;
        s_w[idx] = wbuf[((size_t)(b * T_ + t)) * N_ + rg * RPG + r];
    }
    __syncthreads();

    if (tid < T_) {
        float s = 0.f;
        #pragma unroll 8
        for (int r = 0; r < RPG; ++r) s += s_w[tid * RPG + r];
        wsp[((size_t)(b * WFG + rg)) * T_ + tid] = s;
    }

    float acc[T_][4];
    #pragma unroll
    for (int t = 0; t < T_; ++t) {
        acc[t][0] = 0.f; acc[t][1] = 0.f; acc[t][2] = 0.f; acc[t][3] = 0.f;
    }

    const ushort* Fb = f16 + (size_t)b * N_ * D_;
    for (int r = 0; r < RPG; ++r) {
        const uint2 u = *(const uint2*)(Fb + (size_t)(rg * RPG + r) * D_ + tid * 4);
        __half2 h0 = *(__half2*)&u.x; float2 q0 = __half22float2(h0);
        __half2 h1 = *(__half2*)&u.y; float2 q1 = __half22float2(h1);
        const float f0 = q0.x, f1 = q0.y, f2 = q1.x, f3 = q1.y;
        const float* wr = s_w + r;
        #pragma unroll
        for (int t = 0; t < T_; ++t) {
            const float w = wr[t << 7];
            acc[t][0] = fmaf(w, f0, acc[t][0]);
            acc[t][1] = fmaf(w, f1, acc[t][1]);
            acc[t][2] = fmaf(w, f2, acc[t][2]);
            acc[t][3] = fmaf(w, f3, acc[t][3]);
        }
    }

    float* pb = part + (((size_t)(b * WFG + rg)) * T_) * D_;
    #pragma unroll
    for (int t = 0; t < T_; ++t) {
        float4 v; v.x = acc[t][0]; v.y = acc[t][1]; v.z = acc[t][2]; v.w = acc[t][3];
        *(float4*)(pb + (size_t)t * D_ + tid * 4) = v;
    }
}

// ---------------- final reduce + normalize ----------------
__global__ __launch_bounds__(THR)
void k_red(const float* __restrict__ part, const float* __restrict__ wsp,
           float* __restrict__ out) {
    const int bid = blockIdx.x, b = bid >> 4, t = bid & 15;
    const int tid = threadIdx.x;
    float den = 0.f;
    #pragma unroll
    for (int rg = 0; rg < WFG; ++rg)
        den += wsp[((size_t)(b * WFG + rg)) * T_ + t];
    den += 1e-8f;
    #pragma unroll
    for (int j = 0; j < 3; ++j) {
        const int c = tid + j * 256;
        float s = 0.f;
        #pragma unroll
        for (int rg = 0; rg < WFG; ++rg)
            s += part[(((size_t)(b * WFG + rg)) * T_ + t) * D_ + c];
        out[((size_t)(b * T_ + t)) * D_ + c] = s / den;
    }
}

// ================= fallback: r6 streaming path =================
__global__ __launch_bounds__(THR)
void k_fusedv(const ushort* __restrict__ f16, const float* __restrict__ sel,
              const float* __restrict__ sal, const float* __restrict__ rsal,
              float* __restrict__ mask, float* __restrict__ num,
              float* __restrict__ wsum, float* __restrict__ argv,
              float* __restrict__ args, int* __restrict__ argi) {
    const int blk = blockIdx.x, b = blk >> 5, g = blk & 31;
    const int tid = threadIdx.x, wave = tid >> 6, lane = tid & 63;
    const int h = lane >> 5, s = lane & 31;
    __shared__ __align__(16) float s_red[4 * D_];
    __shared__ float s_wsumW[4];
    __shared__ float s_msal[ROWS_PB];
    __shared__ float s_salL[ROWS_PB];
    const size_t row0 = (size_t)b * N_ + (size_t)g * ROWS_PB;
    const int rbase = b * N_ + g * ROWS_PB;
    const int r0 = wave * ROWS_PW;
    float se[CPL];
    {
        const float4* sp = (const float4*)(sel + (size_t)b * D_ + s * CPL);
        #pragma unroll
        for (int q = 0; q < 6; ++q) {
            float4 v = sp[q];
            se[q*4+0] = v.x; se[q*4+1] = v.y; se[q*4+2] = v.z; se[q*4+3] = v.w;
        }
    }
    float acc[CPL];
    #pragma unroll
    for (int i = 0; i < CPL; ++i) acc[i] = 0.f;
    float wsl = 0.f;
    #pragma unroll
    for (int rp = 0; rp < ROWS_PW / 2; ++rp) {
        const int r = r0 + rp * 2 + h;
        const uint4* dp = (const uint4*)(f16 + (row0 + r) * D_ + s * CPL);
        uint4 u0 = dp[0], u1 = dp[1], u2 = dp[2];
        float f[CPL];
        unpack8(u0, f); unpack8(u1, f + 8); unpack8(u2, f + 16);
        float dot = 0.f;
        #pragma unroll
        for (int i = 0; i < CPL; ++i) dot = fmaf(f[i], se[i], dot);
        dot = half_sum(dot);
        float rs  = rsal[rbase + r];
        float sv  = sal[rbase + r];
        float m   = mask[rbase + r];
        float sim = dot * rs;
        float wr  = (sim > 0.5f) ? (sim * m) : 0.f;
        float nm  = m * (1.0f - fminf(fmaxf(sim, 0.f), 1.f));
        if (s == 0) { mask[rbase + r] = nm; s_msal[r] = sv * nm; s_salL[r] = sv; }
        wsl += wr;
        #pragma unroll
        for (int i = 0; i < CPL; ++i) acc[i] = fmaf(wr, f[i], acc[i]);
    }
    wsl += __shfl_xor(wsl, 32);
    #pragma unroll
    for (int i = 0; i < CPL; ++i) acc[i] += __shfl_xor(acc[i], 32);
    if (h == 0) {
        float4* rw = (float4*)(s_red + wave * D_ + s * CPL);
        #pragma unroll
        for (int q = 0; q < 6; ++q) {
            float4 v;
            v.x = acc[q*4+0]; v.y = acc[q*4+1]; v.z = acc[q*4+2]; v.w = acc[q*4+3];
            rw[q] = v;
        }
    }
    if (lane == 0) s_wsumW[wave] = wsl;
    __syncthreads();
    #pragma unroll
    for (int it = 0; it < 3; ++it) {
        const int c = it * THR + tid;
        float sm = s_red[c] + s_red[D_ + c] + s_red[2*D_ + c] + s_red[3*D_ + c];
        num[((size_t)b * SLABS + g) * D_ + c] = sm;
    }
    if (tid == 0)
        wsum[b*SLABS+g] = s_wsumW[0] + s_wsumW[1] + s_wsumW[2] + s_wsumW[3];
    if (wave == 0) {
        float v  = (lane < ROWS_PB) ? s_msal[lane] : -INFINITY;
        float sv = (lane < ROWS_PB) ? s_salL[lane] : 0.f;
        int   i  = (lane < ROWS_PB) ? (g * ROWS_PB + lane) : 0x7fffffff;
        #pragma unroll
        for (int off = 32; off; off >>= 1) {
            float ov = __shfl_xor(v, off);
            float osv = __shfl_xor(sv, off);
            int   oi = __shfl_xor(i, off);
            if (ov > v || (ov == v && oi < i)) { v = ov; sv = osv; i = oi; }
        }
        if (lane == 0) { argv[b*SLABS+g] = v; args[b*SLABS+g] = sv; argi[b*SLABS+g] = i; }
    }
}

__global__ __launch_bounds__(192)
void k_out(const float* __restrict__ feat, const float* __restrict__ num,
           const float* __restrict__ wsumA, const float* __restrict__ argv,
           const float* __restrict__ args, const int* __restrict__ argi,
           float* __restrict__ sel, float* __restrict__ out, int t) {
    const int b = blockIdx.x >> 2, q = blockIdx.x & 3;
    const int tid = threadIdx.x, lane = tid & 63;
    __shared__ float s_rsel;
    __shared__ int   s_idx;
    __shared__ float s_ws;
    if (tid < 64) {
        float v  = (lane < SLABS) ? argv[b*SLABS + lane] : -INFINITY;
        float sv = (lane < SLABS) ? args[b*SLABS + lane] : 0.f;
        int   i  = (lane < SLABS) ? argi[b*SLABS + lane] : 0x7fffffff;
        float w  = (lane < SLABS) ? wsumA[b*SLABS + lane] : 0.f;
        #pragma unroll
        for (int off = 32; off; off >>= 1) {
            float ov = __shfl_xor(v, off);
            float osv = __shfl_xor(sv, off);
            int   oi = __shfl_xor(i, off);
            w += __shfl_xor(w, off);
            if (ov > v || (ov == v && oi < i)) { v = ov; sv = osv; i = oi; }
        }
        if (lane == 0) { s_idx = i; s_rsel = 1.0f / fmaxf(sv, 1e-12f); s_ws = w; }
    }
    __syncthreads();
    const int c = q * 192 + tid;
    if (t >= 0) {
        float sm = 0.f;
        #pragma unroll 8
        for (int g = 0; g < SLABS; ++g)
            sm += num[((size_t)b * SLABS + g) * D_ + c];
        out[((size_t)b * T_ + t) * D_ + c] = sm / (s_ws + 1e-8f);
    }
    sel[(size_t)b * D_ + c] = feat[((size_t)b * N_ + s_idx) * D_ + c] * s_rsel;
}

extern "C" void kernel_launch(void* const* d_in, const int* in_sizes, int n_in,
                              void* d_out, int out_size, void* d_ws, size_t ws_size,
                              hipStream_t stream) {
    const float* feat = (const float*)d_in[0];
    float* out = (float*)d_out;
    (void)in_sizes; (void)n_in; (void)out_size;

    const size_t n_sal  = (size_t)B_ * N_;
    const size_t n_arg  = (size_t)B_ * SLABS;
    const size_t n_sel  = (size_t)B_ * D_;
    const size_t n_num  = (size_t)B_ * SLABS * D_;
    const size_t n_f16  = (size_t)B_ * N_ * D_;
    const size_t n_G    = (size_t)B_ * N_ * N_;      // f32
    const size_t n_wbuf = (size_t)B_ * T_ * N_;
    const size_t n_part = (size_t)B_ * WFG * T_ * D_;
    const size_t n_wsp  = (size_t)B_ * WFG * T_;

    const size_t f16_bytes = (n_f16 * sizeof(ushort) + 255) & ~(size_t)255;

    const size_t need_gram = f16_bytes
        + (n_G + n_wbuf + n_part + n_wsp + 3*n_sal + 3*n_arg) * sizeof(float) + 4096;
    const size_t need_mk = f16_bytes
        + (3*n_sal + 4*n_arg + n_sel + n_num) * sizeof(float) + 1024;

    if (ws_size >= need_gram) {
        char* base = (char*)d_ws;
        ushort* f16 = (ushort*)base;
        float* p = (float*)(base + f16_bytes);
        float* G     = p;        p += n_G;
        float* wbuf  = p;        p += n_wbuf;
        float* part  = p;        p += n_part;
        float* wsp   = p;        p += n_wsp;
        float* sal   = p;        p += n_sal;
        float* rsal  = p;        p += n_sal;
        float* mask  = p;        p += n_sal;
        float* argvD = p;        p += n_arg;
        float* argsD = p;        p += n_arg;
        int*   argiD = (int*)p;  p += n_arg;

        k_sal16v<<<B_*SLABS, THR, 0, stream>>>(feat, f16, sal, rsal, mask,
                                               argvD, argsD, argiD);
        k_gram<<<B_*NTILE, THR, 0, stream>>>(f16, G);
        k_slots<<<B_, 64, 0, stream>>>(G, sal, rsal, wbuf);
        k_wf<<<B_*WFG, WFTHR, 0, stream>>>(f16, wbuf, part, wsp);
        k_red<<<B_*T_, THR, 0, stream>>>(part, wsp, out);
        return;
    }

    if (ws_size >= need_mk) {
        char* base = (char*)d_ws;
        ushort* f16 = (ushort*)base;
        float* p = (float*)(base + f16_bytes);
        float* sal  = p;            p += n_sal;
        float* rsal = p;            p += n_sal;
        float* mask = p;            p += n_sal;
        float* argv = p;            p += n_arg;
        float* args = p;            p += n_arg;
        int*   argi = (int*)p;      p += n_arg;
        float* wsum = p;            p += n_arg;
        float* sel  = p;            p += n_sel;
        float* num  = p;            p += n_num;

        k_sal16v<<<B_*SLABS, THR, 0, stream>>>(feat, f16, sal, rsal, mask, argv, args, argi);
        k_out<<<B_*4, 192, 0, stream>>>(feat, num, wsum, argv, args, argi, sel, out, -1);
        for (int t = 0; t < T_; ++t) {
            k_fusedv<<<B_*SLABS, THR, 0, stream>>>(f16, sel, sal, rsal, mask,
                                                   num, wsum, argv, args, argi);
            k_out<<<B_*4, 192, 0, stream>>>(feat, num, wsum, argv, args, argi, sel, out, t);
        }
        return;
    }
}

// Round 15
// 237.517 us; speedup vs baseline: 1.2467x; 1.2467x over previous
//
#include <hip/hip_runtime.h>
#include <hip/hip_fp16.h>
#include <math.h>

#define B_      64
#define N_      1024
#define D_      768
#define T_      16
#define SLABS   32
#define ROWS_PB 32
#define ROWS_PW 8
#define THR     256
#define CPL     24
#define NTILE   36          // upper-triangle 8x8 tile grid
#define WFG     8           // k_wf row groups
#define WFTHR   192         // k_wf threads (4 cols each)

typedef _Float16 half8 __attribute__((ext_vector_type(8)));
typedef float    f32x4 __attribute__((ext_vector_type(4)));

__device__ __forceinline__ float wave_sum(float v) {
    #pragma unroll
    for (int off = 32; off; off >>= 1) v += __shfl_xor(v, off);
    return v;
}
__device__ __forceinline__ float half_sum(float v) {
    #pragma unroll
    for (int off = 16; off; off >>= 1) v += __shfl_xor(v, off);
    return v;
}
__device__ __forceinline__ unsigned pack2(float a, float b) {
    __half2 h = __float22half2_rn(make_float2(a, b));
    return *(unsigned*)&h;
}
__device__ __forceinline__ void unpack8(uint4 u, float* f) {
    __half2 h; float2 q;
    h = *(__half2*)&u.x; q = __half22float2(h); f[0] = q.x; f[1] = q.y;
    h = *(__half2*)&u.y; q = __half22float2(h); f[2] = q.x; f[3] = q.y;
    h = *(__half2*)&u.z; q = __half22float2(h); f[4] = q.x; f[5] = q.y;
    h = *(__half2*)&u.w; q = __half22float2(h); f[6] = q.x; f[7] = q.y;
}

// async global->LDS, 16B per lane (dest = wave-uniform base + lane*16, G21)
__device__ __forceinline__ void gload_lds16(const void* g, void* l) {
    __builtin_amdgcn_global_load_lds(
        (__attribute__((address_space(1))) void*)(g),
        (__attribute__((address_space(3))) void*)(l), 16, 0, 0);
}

// ---------------- pass 0: saliency + f16 pack ----------------
__global__ __launch_bounds__(THR)
void k_sal16v(const float* __restrict__ feat, ushort* __restrict__ f16,
              float* __restrict__ sal, float* __restrict__ rsal,
              float* __restrict__ mask, float* __restrict__ argv,
              float* __restrict__ args, int* __restrict__ argi) {
    const int blk = blockIdx.x, b = blk >> 5, g = blk & 31;
    const int tid = threadIdx.x, wave = tid >> 6, lane = tid & 63;
    const int h = lane >> 5, s = lane & 31;
    __shared__ float s_sal[ROWS_PB];

    const size_t row0 = (size_t)b * N_ + (size_t)g * ROWS_PB;
    const int r0 = wave * ROWS_PW;

    #pragma unroll
    for (int rp = 0; rp < ROWS_PW / 2; ++rp) {
        const int r = r0 + rp * 2 + h;
        const float4* fp4 = (const float4*)(feat + (row0 + r) * D_ + s * CPL);
        float4 a0 = fp4[0], a1 = fp4[1], a2 = fp4[2], a3 = fp4[3], a4 = fp4[4], a5 = fp4[5];
        uint4 w0, w1, w2;
        w0.x = pack2(a0.x, a0.y); w0.y = pack2(a0.z, a0.w);
        w0.z = pack2(a1.x, a1.y); w0.w = pack2(a1.z, a1.w);
        w1.x = pack2(a2.x, a2.y); w1.y = pack2(a2.z, a2.w);
        w1.z = pack2(a3.x, a3.y); w1.w = pack2(a3.z, a3.w);
        w2.x = pack2(a4.x, a4.y); w2.y = pack2(a4.z, a4.w);
        w2.z = pack2(a5.x, a5.y); w2.w = pack2(a5.z, a5.w);
        uint4* wp = (uint4*)(f16 + (row0 + r) * D_ + s * CPL);
        wp[0] = w0; wp[1] = w1; wp[2] = w2;

        float ss = a0.x*a0.x + a0.y*a0.y + a0.z*a0.z + a0.w*a0.w
                 + a1.x*a1.x + a1.y*a1.y + a1.z*a1.z + a1.w*a1.w
                 + a2.x*a2.x + a2.y*a2.y + a2.z*a2.z + a2.w*a2.w
                 + a3.x*a3.x + a3.y*a3.y + a3.z*a3.z + a3.w*a3.w
                 + a4.x*a4.x + a4.y*a4.y + a4.z*a4.z + a4.w*a4.w
                 + a5.x*a5.x + a5.y*a5.y + a5.z*a5.z + a5.w*a5.w;
        ss = half_sum(ss);
        if (s == 0) s_sal[r] = sqrtf(ss);
    }
    __syncthreads();

    const int rg = b * N_ + g * ROWS_PB;
    if (tid < ROWS_PB) {
        float n = s_sal[tid];
        sal[rg + tid]  = n;
        rsal[rg + tid] = 1.0f / fmaxf(n, 1e-12f);
        mask[rg + tid] = 1.0f;
    }
    if (wave == 0) {
        float v  = (lane < ROWS_PB) ? s_sal[lane] : -INFINITY;
        float sv = v;
        int   i  = (lane < ROWS_PB) ? (g * ROWS_PB + lane) : 0x7fffffff;
        #pragma unroll
        for (int off = 32; off; off >>= 1) {
            float ov = __shfl_xor(v, off);
            float osv = __shfl_xor(sv, off);
            int   oi = __shfl_xor(i, off);
            if (ov > v || (ov == v && oi < i)) { v = ov; sv = osv; i = oi; }
        }
        if (lane == 0) { argv[b*SLABS+g] = v; args[b*SLABS+g] = sv; argi[b*SLABS+g] = i; }
    }
}

// ---------------- Gram GEMM (upper-triangle, XCD-grouped, gload_lds, f32 G) ----------------
__global__ __launch_bounds__(THR)
void k_gram(const ushort* __restrict__ f16, float* __restrict__ G) {
    const int bid = blockIdx.x;
    const int xcd = bid & 7, slot = bid >> 3;
    const int batch = xcd + 8 * (slot / NTILE);
    int u = slot % NTILE;
    int trow = 0, cnt = 8;
    while (u >= cnt) { u -= cnt; --cnt; ++trow; }
    const int tcol = trow + u;
    const bool diag = (trow == tcol);

    const int tid = threadIdx.x, wave = tid >> 6, lane = tid & 63;
    const int wr = wave >> 1, wc = wave & 1;

    __shared__ __align__(16) ushort lA[128 * 64];
    __shared__ __align__(16) ushort lB[128 * 64];

    const ushort* Fb = f16 + (size_t)batch * N_ * D_;
    const int row0 = trow * 128, col0 = tcol * 128;

    f32x4 acc[4][4];
    #pragma unroll
    for (int i = 0; i < 4; ++i)
        #pragma unroll
        for (int j = 0; j < 4; ++j)
            acc[i][j] = (f32x4){0.f, 0.f, 0.f, 0.f};

    const ushort* lBr = diag ? lA : lB;

    for (int k0 = 0; k0 < D_; k0 += 64) {
        #pragma unroll
        for (int i = 0; i < 4; ++i) {
            const int d  = i * THR + tid;
            const int r  = d >> 3;
            const int kc = (d & 7) ^ (r & 7);
            gload_lds16(Fb + (size_t)(row0 + r) * D_ + k0 + kc * 8, lA + (size_t)d * 8);
            if (!diag)
                gload_lds16(Fb + (size_t)(col0 + r) * D_ + k0 + kc * 8, lB + (size_t)d * 8);
        }
        __syncthreads();

        #pragma unroll
        for (int ks = 0; ks < 2; ++ks) {
            half8 af[4], bf[4];
            #pragma unroll
            for (int fr = 0; fr < 4; ++fr) {
                const int rl = wr * 64 + fr * 16 + (lane & 15);
                const int kch = ks * 4 + (lane >> 4);
                af[fr] = *(const half8*)(lA + rl * 64 + ((kch ^ (rl & 7)) * 8));
            }
            #pragma unroll
            for (int fc = 0; fc < 4; ++fc) {
                const int cl = wc * 64 + fc * 16 + (lane & 15);
                const int kch = ks * 4 + (lane >> 4);
                bf[fc] = *(const half8*)(lBr + cl * 64 + ((kch ^ (cl & 7)) * 8));
            }
            #pragma unroll
            for (int fr = 0; fr < 4; ++fr)
                #pragma unroll
                for (int fc = 0; fc < 4; ++fc)
                    acc[fr][fc] = __builtin_amdgcn_mfma_f32_16x16x32_f16(
                        af[fr], bf[fc], acc[fr][fc], 0, 0, 0);
        }
        __syncthreads();
    }

    // epilogue: C/D mapping col=lane&15, row=(lane>>4)*4+q  [m89]
    float* Gb = G + ((size_t)batch << 20);
    #pragma unroll
    for (int fr = 0; fr < 4; ++fr) {
        #pragma unroll
        for (int fc = 0; fc < 4; ++fc) {
            const int rbase = row0 + wr * 64 + fr * 16 + (lane >> 4) * 4;
            const int c     = col0 + wc * 64 + fc * 16 + (lane & 15);
            #pragma unroll
            for (int q = 0; q < 4; ++q)
                Gb[(size_t)(rbase + q) * N_ + c] = acc[fr][fc][q];
        }
    }
}

// ---------------- slot loop: 1 wave per batch, register state, zero barriers ----------------
__global__ __launch_bounds__(64)
void k_slots(const float* __restrict__ G, const float* __restrict__ sal,
             const float* __restrict__ rsal, float* __restrict__ wbuf) {
    const int b = blockIdx.x, lane = threadIdx.x;
    const float* Gb = G + ((size_t)b << 20);

    float lsal[16], lrsal[16], lmask[16], lmsal[16];
    #pragma unroll
    for (int k = 0; k < 16; ++k) {
        const int n = lane + (k << 6);
        lsal[k]  = sal[b * N_ + n];
        lrsal[k] = rsal[b * N_ + n];
        lmask[k] = 1.0f;
        lmsal[k] = lsal[k];
    }

    for (int t = 0; t < T_; ++t) {
        float v = lmsal[0]; int i = lane;
        #pragma unroll
        for (int k = 1; k < 16; ++k) {
            if (lmsal[k] > v) { v = lmsal[k]; i = lane + (k << 6); }
        }
        #pragma unroll
        for (int off = 32; off; off >>= 1) {
            float ov = __shfl_xor(v, off);
            int   oi = __shfl_xor(i, off);
            if (ov > v || (ov == v && oi < i)) { v = ov; i = oi; }
        }
        const int idx = i;
        const float rsi = rsal[b * N_ + idx];   // broadcast load

        #pragma unroll
        for (int k = 0; k < 16; ++k) {
            const int n = lane + (k << 6);
            float gv  = (n >= idx) ? Gb[(size_t)idx * N_ + n]
                                   : Gb[(size_t)n * N_ + idx];   // symmetric mirror
            float sim = gv * lrsal[k] * rsi;
            float m   = lmask[k];
            float w   = (sim > 0.5f) ? (sim * m) : 0.f;
            float nm  = m * (1.0f - fminf(fmaxf(sim, 0.f), 1.f));
            lmask[k] = nm;
            lmsal[k] = lsal[k] * nm;
            wbuf[((size_t)(b * T_ + t)) * N_ + n] = w;
        }
    }
}

// ---------------- W*F partials + per-rg wsum partials ----------------
__global__ __launch_bounds__(WFTHR)
void k_wf(const ushort* __restrict__ f16, const float* __restrict__ wbuf,
          float* __restrict__ part, float* __restrict__ wsp) {
    const int bid = blockIdx.x, b = bid >> 3, rg = bid & 7;
    const int tid = threadIdx.x;
    const int RPG = N_ / WFG;   // 128

    __shared__ float s_w[T_ * (N_ / WFG)];

    for (int idx = tid; idx < T_ * RPG; idx += WFTHR) {
        const int t = idx >> 7, r = idx & 127;
        s_w[idx] = wbuf[((size_t)(b * T_ + t)) * N_ + rg * RPG + r];
    }
    __syncthreads();

    // per-rg wsum partials
    if (tid < T_) {
        float s = 0.f;
        #pragma unroll 8
        for (int r = 0; r < RPG; ++r) s += s_w[tid * RPG + r];
        wsp[((size_t)(b * WFG + rg)) * T_ + tid] = s;
    }

    float acc[T_][4];
    #pragma unroll
    for (int t = 0; t < T_; ++t) {
        acc[t][0] = 0.f; acc[t][1] = 0.f; acc[t][2] = 0.f; acc[t][3] = 0.f;
    }

    const ushort* Fb = f16 + (size_t)b * N_ * D_;
    for (int r = 0; r < RPG; ++r) {
        const uint2 u = *(const uint2*)(Fb + (size_t)(rg * RPG + r) * D_ + tid * 4);
        __half2 h0 = *(__half2*)&u.x; float2 q0 = __half22float2(h0);
        __half2 h1 = *(__half2*)&u.y; float2 q1 = __half22float2(h1);
        const float f0 = q0.x, f1 = q0.y, f2 = q1.x, f3 = q1.y;
        const float* wr = s_w + r;
        #pragma unroll
        for (int t = 0; t < T_; ++t) {
            const float w = wr[t << 7];
            acc[t][0] = fmaf(w, f0, acc[t][0]);
            acc[t][1] = fmaf(w, f1, acc[t][1]);
            acc[t][2] = fmaf(w, f2, acc[t][2]);
            acc[t][3] = fmaf(w, f3, acc[t][3]);
        }
    }

    float* pb = part + (((size_t)(b * WFG + rg)) * T_) * D_;
    #pragma unroll
    for (int t = 0; t < T_; ++t) {
        float4 v; v.x = acc[t][0]; v.y = acc[t][1]; v.z = acc[t][2]; v.w = acc[t][3];
        *(float4*)(pb + (size_t)t * D_ + tid * 4) = v;
    }
}

// ---------------- final reduce + normalize ----------------
__global__ __launch_bounds__(THR)
void k_red(const float* __restrict__ part, const float* __restrict__ wsp,
           float* __restrict__ out) {
    const int bid = blockIdx.x, b = bid >> 4, t = bid & 15;
    const int tid = threadIdx.x;
    float den = 0.f;
    #pragma unroll
    for (int rg = 0; rg < WFG; ++rg)
        den += wsp[((size_t)(b * WFG + rg)) * T_ + t];
    den += 1e-8f;
    #pragma unroll
    for (int j = 0; j < 3; ++j) {
        const int c = tid + j * 256;
        float s = 0.f;
        #pragma unroll
        for (int rg = 0; rg < WFG; ++rg)
            s += part[(((size_t)(b * WFG + rg)) * T_ + t) * D_ + c];
        out[((size_t)(b * T_ + t)) * D_ + c] = s / den;
    }
}

// ================= fallback: r6 streaming path =================
__global__ __launch_bounds__(THR)
void k_fusedv(const ushort* __restrict__ f16, const float* __restrict__ sel,
              const float* __restrict__ sal, const float* __restrict__ rsal,
              float* __restrict__ mask, float* __restrict__ num,
              float* __restrict__ wsum, float* __restrict__ argv,
              float* __restrict__ args, int* __restrict__ argi) {
    const int blk = blockIdx.x, b = blk >> 5, g = blk & 31;
    const int tid = threadIdx.x, wave = tid >> 6, lane = tid & 63;
    const int h = lane >> 5, s = lane & 31;
    __shared__ __align__(16) float s_red[4 * D_];
    __shared__ float s_wsumW[4];
    __shared__ float s_msal[ROWS_PB];
    __shared__ float s_salL[ROWS_PB];
    const size_t row0 = (size_t)b * N_ + (size_t)g * ROWS_PB;
    const int rbase = b * N_ + g * ROWS_PB;
    const int r0 = wave * ROWS_PW;
    float se[CPL];
    {
        const float4* sp = (const float4*)(sel + (size_t)b * D_ + s * CPL);
        #pragma unroll
        for (int q = 0; q < 6; ++q) {
            float4 v = sp[q];
            se[q*4+0] = v.x; se[q*4+1] = v.y; se[q*4+2] = v.z; se[q*4+3] = v.w;
        }
    }
    float acc[CPL];
    #pragma unroll
    for (int i = 0; i < CPL; ++i) acc[i] = 0.f;
    float wsl = 0.f;
    #pragma unroll
    for (int rp = 0; rp < ROWS_PW / 2; ++rp) {
        const int r = r0 + rp * 2 + h;
        const uint4* dp = (const uint4*)(f16 + (row0 + r) * D_ + s * CPL);
        uint4 u0 = dp[0], u1 = dp[1], u2 = dp[2];
        float f[CPL];
        unpack8(u0, f); unpack8(u1, f + 8); unpack8(u2, f + 16);
        float dot = 0.f;
        #pragma unroll
        for (int i = 0; i < CPL; ++i) dot = fmaf(f[i], se[i], dot);
        dot = half_sum(dot);
        float rs  = rsal[rbase + r];
        float sv  = sal[rbase + r];
        float m   = mask[rbase + r];
        float sim = dot * rs;
        float wr  = (sim > 0.5f) ? (sim * m) : 0.f;
        float nm  = m * (1.0f - fminf(fmaxf(sim, 0.f), 1.f));
        if (s == 0) { mask[rbase + r] = nm; s_msal[r] = sv * nm; s_salL[r] = sv; }
        wsl += wr;
        #pragma unroll
        for (int i = 0; i < CPL; ++i) acc[i] = fmaf(wr, f[i], acc[i]);
    }
    wsl += __shfl_xor(wsl, 32);
    #pragma unroll
    for (int i = 0; i < CPL; ++i) acc[i] += __shfl_xor(acc[i], 32);
    if (h == 0) {
        float4* rw = (float4*)(s_red + wave * D_ + s * CPL);
        #pragma unroll
        for (int q = 0; q < 6; ++q) {
            float4 v;
            v.x = acc[q*4+0]; v.y = acc[q*4+1]; v.z = acc[q*4+2]; v.w = acc[q*4+3];
            rw[q] = v;
        }
    }
    if (lane == 0) s_wsumW[wave] = wsl;
    __syncthreads();
    #pragma unroll
    for (int it = 0; it < 3; ++it) {
        const int c = it * THR + tid;
        float sm = s_red[c] + s_red[D_ + c] + s_red[2*D_ + c] + s_red[3*D_ + c];
        num[((size_t)b * SLABS + g) * D_ + c] = sm;
    }
    if (tid == 0)
        wsum[b*SLABS+g] = s_wsumW[0] + s_wsumW[1] + s_wsumW[2] + s_wsumW[3];
    if (wave == 0) {
        float v  = (lane < ROWS_PB) ? s_msal[lane] : -INFINITY;
        float sv = (lane < ROWS_PB) ? s_salL[lane] : 0.f;
        int   i  = (lane < ROWS_PB) ? (g * ROWS_PB + lane) : 0x7fffffff;
        #pragma unroll
        for (int off = 32; off; off >>= 1) {
            float ov = __shfl_xor(v, off);
            float osv = __shfl_xor(sv, off);
            int   oi = __shfl_xor(i, off);
            if (ov > v || (ov == v && oi < i)) { v = ov; sv = osv; i = oi; }
        }
        if (lane == 0) { argv[b*SLABS+g] = v; args[b*SLABS+g] = sv; argi[b*SLABS+g] = i; }
    }
}

__global__ __launch_bounds__(192)
void k_out(const float* __restrict__ feat, const float* __restrict__ num,
           const float* __restrict__ wsumA, const float* __restrict__ argv,
           const float* __restrict__ args, const int* __restrict__ argi,
           float* __restrict__ sel, float* __restrict__ out, int t) {
    const int b = blockIdx.x >> 2, q = blockIdx.x & 3;
    const int tid = threadIdx.x, lane = tid & 63;
    __shared__ float s_rsel;
    __shared__ int   s_idx;
    __shared__ float s_ws;
    if (tid < 64) {
        float v  = (lane < SLABS) ? argv[b*SLABS + lane] : -INFINITY;
        float sv = (lane < SLABS) ? args[b*SLABS + lane] : 0.f;
        int   i  = (lane < SLABS) ? argi[b*SLABS + lane] : 0x7fffffff;
        float w  = (lane < SLABS) ? wsumA[b*SLABS + lane] : 0.f;
        #pragma unroll
        for (int off = 32; off; off >>= 1) {
            float ov = __shfl_xor(v, off);
            float osv = __shfl_xor(sv, off);
            int   oi = __shfl_xor(i, off);
            w += __shfl_xor(w, off);
            if (ov > v || (ov == v && oi < i)) { v = ov; sv = osv; i = oi; }
        }
        if (lane == 0) { s_idx = i; s_rsel = 1.0f / fmaxf(sv, 1e-12f); s_ws = w; }
    }
    __syncthreads();
    const int c = q * 192 + tid;
    if (t >= 0) {
        float sm = 0.f;
        #pragma unroll 8
        for (int g = 0; g < SLABS; ++g)
            sm += num[((size_t)b * SLABS + g) * D_ + c];
        out[((size_t)b * T_ + t) * D_ + c] = sm / (s_ws + 1e-8f);
    }
    sel[(size_t)b * D_ + c] = feat[((size_t)b * N_ + s_idx) * D_ + c] * s_rsel;
}

extern "C" void kernel_launch(void* const* d_in, const int* in_sizes, int n_in,
                              void* d_out, int out_size, void* d_ws, size_t ws_size,
                              hipStream_t stream) {
    const float* feat = (const float*)d_in[0];
    float* out = (float*)d_out;
    (void)in_sizes; (void)n_in; (void)out_size;

    const size_t n_sal  = (size_t)B_ * N_;
    const size_t n_arg  = (size_t)B_ * SLABS;
    const size_t n_sel  = (size_t)B_ * D_;
    const size_t n_num  = (size_t)B_ * SLABS * D_;
    const size_t n_f16  = (size_t)B_ * N_ * D_;
    const size_t n_G    = (size_t)B_ * N_ * N_;      // f32
    const size_t n_wbuf = (size_t)B_ * T_ * N_;
    const size_t n_part = (size_t)B_ * WFG * T_ * D_;
    const size_t n_wsp  = (size_t)B_ * WFG * T_;

    const size_t f16_bytes = (n_f16 * sizeof(ushort) + 255) & ~(size_t)255;

    const size_t need_gram = f16_bytes
        + (n_G + n_wbuf + n_part + n_wsp + 3*n_sal + 3*n_arg) * sizeof(float) + 4096;
    const size_t need_mk = f16_bytes
        + (3*n_sal + 4*n_arg + n_sel + n_num) * sizeof(float) + 1024;

    if (ws_size >= need_gram) {
        char* base = (char*)d_ws;
        ushort* f16 = (ushort*)base;
        float* p = (float*)(base + f16_bytes);
        float* G     = p;        p += n_G;
        float* wbuf  = p;        p += n_wbuf;
        float* part  = p;        p += n_part;
        float* wsp   = p;        p += n_wsp;
        float* sal   = p;        p += n_sal;
        float* rsal  = p;        p += n_sal;
        float* mask  = p;        p += n_sal;
        float* argvD = p;        p += n_arg;
        float* argsD = p;        p += n_arg;
        int*   argiD = (int*)p;  p += n_arg;

        k_sal16v<<<B_*SLABS, THR, 0, stream>>>(feat, f16, sal, rsal, mask,
                                               argvD, argsD, argiD);
        k_gram<<<B_*NTILE, THR, 0, stream>>>(f16, G);
        k_slots<<<B_, 64, 0, stream>>>(G, sal, rsal, wbuf);
        k_wf<<<B_*WFG, WFTHR, 0, stream>>>(f16, wbuf, part, wsp);
        k_red<<<B_*T_, THR, 0, stream>>>(part, wsp, out);
        return;
    }

    if (ws_size >= need_mk) {
        char* base = (char*)d_ws;
        ushort* f16 = (ushort*)base;
        float* p = (float*)(base + f16_bytes);
        float* sal  = p;            p += n_sal;
        float* rsal = p;            p += n_sal;
        float* mask = p;            p += n_sal;
        float* argv = p;            p += n_arg;
        float* args = p;            p += n_arg;
        int*   argi = (int*)p;      p += n_arg;
        float* wsum = p;            p += n_arg;
        float* sel  = p;            p += n_sel;
        float* num  = p;            p += n_num;

        k_sal16v<<<B_*SLABS, THR, 0, stream>>>(feat, f16, sal, rsal, mask, argv, args, argi);
        k_out<<<B_*4, 192, 0, stream>>>(feat, num, wsum, argv, args, argi, sel, out, -1);
        for (int t = 0; t < T_; ++t) {
            k_fusedv<<<B_*SLABS, THR, 0, stream>>>(f16, sel, sal, rsal, mask,
                                                   num, wsum, argv, args, argi);
            k_out<<<B_*4, 192, 0, stream>>>(feat, num, wsum, argv, args, argi, sel, out, t);
        }
        return;
    }
}